// Round 8
// baseline (211.542 us; speedup 1.0000x reference)
//
#include <hip/hip_runtime.h>
#include <hip/hip_bf16.h>

typedef __bf16 bf16x8 __attribute__((ext_vector_type(8)));
typedef __bf16 bf16x4 __attribute__((ext_vector_type(4)));
typedef float  f32x4  __attribute__((ext_vector_type(4)));
typedef unsigned short u16;
typedef unsigned int   u32;

#define GLOBAL_AS __attribute__((address_space(1)))
#define LDS_AS    __attribute__((address_space(3)))

#define LOG2E 1.44269504088896f

__device__ __forceinline__ void gload_lds16(const void* g, void* l) {
    __builtin_amdgcn_global_load_lds((GLOBAL_AS void*)g, (LDS_AS void*)l, 16, 0, 0);
}

__device__ __forceinline__ u16 f2b(float f) {
    union { float f; u32 u; } c; c.f = f;
    u32 u = c.u;
    u32 r = (u + 0x7FFFu + ((u >> 16) & 1u)) >> 16;   // RNE
    return (u16)r;
}

// ---------------- conversion kernels ----------------

__global__ void cvt_x_kernel(const float* __restrict__ x, u16* __restrict__ out, int n4) {
    int i = blockIdx.x * blockDim.x + threadIdx.x;
    if (i < n4) {
        float4 v = ((const float4*)x)[i];
        u16 o[4] = { f2b(v.x), f2b(v.y), f2b(v.z), f2b(v.w) };
        ((uint2*)out)[i] = *(uint2*)o;
    }
}

// dst[j][k] = src[k][j] (768x768), f32 -> bf16
__global__ void transpose_cvt_kernel(const float* __restrict__ src, u16* __restrict__ dst) {
    __shared__ float tile[32][33];
    int jt = blockIdx.x * 32, kt = blockIdx.y * 32;
    int tx = threadIdx.x, ty = threadIdx.y;           // block (32,8)
#pragma unroll
    for (int i = 0; i < 4; ++i)
        tile[ty + i * 8][tx] = src[(size_t)(kt + ty + i * 8) * 768 + jt + tx];
    __syncthreads();
#pragma unroll
    for (int i = 0; i < 4; ++i)
        dst[(size_t)(jt + ty + i * 8) * 768 + kt + tx] = f2b(tile[tx][ty + i * 8]);
}

__global__ void pack_bias_kernel(const float* __restrict__ bq, const float* __restrict__ bk,
                                 const float* __restrict__ bv, float* __restrict__ out) {
    int i = blockIdx.x * blockDim.x + threadIdx.x;
    if (i < 2304) out[i] = (i < 768) ? bq[i] : (i < 1536 ? bk[i - 768] : bv[i - 1536]);
}

// ---------------- GEMM: C[M][ldc] = A[M][K] @ Bt[N][K]^T + bias ----------------
// VSPLIT: output cols [0,1536) -> C (ldc), cols [1536,2304) -> VT[col-1536][row] (transposed,
// 8B packed stores; fuses the V transpose into the epilogue).
template <typename OutT, bool VSPLIT>
__global__ __launch_bounds__(256) void gemm_bt_kernel(
    const u16* __restrict__ A, const u16* __restrict__ Bt,
    const float* __restrict__ bias, OutT* __restrict__ C, u16* __restrict__ VT,
    int M, int N, int K, int ldc)
{
    __shared__ u16 As[128 * 64];
    __shared__ u16 Bs[128 * 64];
    const int lane = threadIdx.x & 63;
    const int w    = threadIdx.x >> 6;
    const int wr   = w >> 1, wc = w & 1;              // 2x2 waves -> 64x64 each
    const int m0   = blockIdx.y * 128, n0 = blockIdx.x * 128;

    f32x4 acc[4][4] = {};

    for (int k0 = 0; k0 < K; k0 += 64) {
        __syncthreads();
#pragma unroll
        for (int i = 0; i < 4; ++i) {
            int ci0 = w * 64 + i * 256;               // wave-uniform chunk base
            int ci  = ci0 + lane;
            int row = ci >> 3, col = (ci & 7) << 3;
            gload_lds16(A  + (size_t)(m0 + row) * K + k0 + col, (void*)(As + ci0 * 8));
            gload_lds16(Bt + (size_t)(n0 + row) * K + k0 + col, (void*)(Bs + ci0 * 8));
        }
        asm volatile("s_waitcnt vmcnt(0)" ::: "memory");
        __syncthreads();

#pragma unroll
        for (int ks = 0; ks < 2; ++ks) {
            const int koff = ks * 32 + (lane >> 4) * 8;
            bf16x8 af[4], bfr[4];
#pragma unroll
            for (int i = 0; i < 4; ++i)
                af[i] = *(const bf16x8*)&As[(wr * 64 + i * 16 + (lane & 15)) * 64 + koff];
#pragma unroll
            for (int j = 0; j < 4; ++j)
                bfr[j] = *(const bf16x8*)&Bs[(wc * 64 + j * 16 + (lane & 15)) * 64 + koff];
#pragma unroll
            for (int i = 0; i < 4; ++i)
#pragma unroll
                for (int j = 0; j < 4; ++j)
                    acc[i][j] = __builtin_amdgcn_mfma_f32_16x16x32_bf16(af[i], bfr[j], acc[i][j], 0, 0, 0);
        }
    }

    const bool vblk = VSPLIT && (n0 >= 1536);         // uniform per block (1536 % 128 == 0)
#pragma unroll
    for (int j = 0; j < 4; ++j) {
        int col = n0 + wc * 64 + j * 16 + (lane & 15);
        float bv = bias[col];
#pragma unroll
        for (int i = 0; i < 4; ++i) {
            int row = m0 + wr * 64 + i * 16 + ((lane >> 4) << 2);
            if (vblk) {
                u16 o[4];
#pragma unroll
                for (int r = 0; r < 4; ++r) o[r] = f2b(acc[i][j][r] + bv);
                *(uint2*)(VT + (size_t)(col - 1536) * 8192 + row) = *(uint2*)o;
            } else {
#pragma unroll
                for (int r = 0; r < 4; ++r) {
                    float v = acc[i][j][r] + bv;
                    if constexpr (sizeof(OutT) == 2)
                        C[(size_t)(row + r) * ldc + col] = (OutT)f2b(v);
                    else
                        C[(size_t)(row + r) * ldc + col] = (OutT)v;
                }
            }
        }
    }
}

// ---------------- flash attention v8: QBLK=128 (32 q/wave) ----------------
// QK: [B*S][1536] bf16 (q | k).  VT: [768 = h*64+d][8192 = b*2048+s] bf16.
// 32 q-rows per wave: K/V LDS tiles are read ONCE per wave regardless of q-count,
// so per-q LDS traffic halves vs 16 q/wave (LDS BW is the measured bottleneck).
// Grid 768 = exactly 3 blocks/CU; LDS 48 KB -> 3 resident, no tail quantization.
// Swapped QK^T (S^T[k][q], k lane-local), unshifted exp2 softmax (scores bounded),
// dbuf K/V with 1 barrier/iter, XOR-swizzled LDS throughout.
__global__ __launch_bounds__(256) void attn_kernel(
    const u16* __restrict__ QK, const u16* __restrict__ VT,
    const float* __restrict__ mask, u16* __restrict__ Comb)
{
    __shared__ u16 Ks[2][64 * 64];     // 16 KB
    __shared__ u16 Vs[2][64 * 64];     // 16 KB
    __shared__ u16 Pq[4 * 32 * 64];    // 16 KB  -> total 48 KB = 3 blocks/CU
    const int lane = threadIdx.x & 63;
    const int w    = threadIdx.x >> 6;
    const int g    = lane >> 4;
    const int l15  = lane & 15;
    const int l7   = lane & 7;
    const int q0   = blockIdx.x * 128;
    const int bh   = blockIdx.y;
    const int b    = bh / 12, h = bh % 12;
    const size_t rowbase = (size_t)b * 2048;
    const u16* Qg = QK + rowbase * 1536 + h * 64;
    const u16* Kg = QK + rowbase * 1536 + 768 + h * 64;
    const u16* Vg = VT + (size_t)(h * 64) * 8192 + b * 2048;  // row d (stride 8192), col s
    const float* mbase = mask + b * 2048 + (g << 2);

    // hoisted per-lane staging addresses (affine in kt)
    const int sci  = w * 64 + lane;                   // chunk index for i=0 (i=1: +256)
    const int srow = sci >> 3;                        // k-row / d-row
    const int kc   = ((sci & 7) ^ (srow & 7)) << 3;   // swizzle col
    const u16* kg0 = Kg + (size_t)srow * 1536 + kc;
    const u16* kg1 = Kg + (size_t)(srow + 32) * 1536 + kc;
    const u16* vg0 = Vg + (size_t)srow * 8192 + kc;
    const u16* vg1 = Vg + (size_t)(srow + 32) * 8192 + kc;
    u16* const ksd0 = (u16*)Ks + (w * 64) * 8;        // LDS dest (buffer 0); +4096 for buffer 1
    u16* const ksd1 = ksd0 + 256 * 8;
    u16* const vsd0 = (u16*)Vs + (w * 64) * 8;
    u16* const vsd1 = vsd0 + 256 * 8;

    // prologue: stage K/V tile 0
    gload_lds16(kg0, (void*)ksd0);
    gload_lds16(kg1, (void*)ksd1);
    gload_lds16(vg0, (void*)vsd0);
    gload_lds16(vg1, (void*)vsd1);

    // Q fragments scaled by 0.125 * log2(e); wave owns rows q0 + w*32 .. +31
    bf16x8 qf[2][2];                                  // [qb][ks]
#pragma unroll
    for (int qb = 0; qb < 2; ++qb)
#pragma unroll
        for (int ks = 0; ks < 2; ++ks) {
            int row = q0 + w * 32 + qb * 16 + l15;
            int d   = ks * 32 + g * 8;
            bf16x8 v = *(const bf16x8*)(Qg + (size_t)row * 1536 + d);
            bf16x8 s;
#pragma unroll
            for (int j = 0; j < 8; ++j) s[j] = (__bf16)((float)v[j] * (0.125f * LOG2E));
            qf[qb][ks] = s;
        }

    f32x4 o_acc[2][4] = {};                           // [qb][dn]
    float l_run[2] = { 0.f, 0.f };                    // per lane: q = qb*16 + l15
    u16* Pw = Pq + w * 32 * 64;
    const int src_row = (lane & 48) + (g << 2);

    asm volatile("s_waitcnt vmcnt(0)" ::: "memory");
    __syncthreads();

    for (int kt = 0; kt < 32; ++kt) {
        const int cur = kt & 1;
        const int k0  = kt * 64;

        // mask loads first (vm ops 1-4): their waitcnt won't drain staging
        f32x4 mv[4];
#pragma unroll
        for (int n = 0; n < 4; ++n)
            mv[n] = *(const f32x4*)(mbase + k0 + n * 16);

        // stage tile t+1 into alt buffer (affine addresses; peeled on last iter)
        if (kt < 31) {
            const size_t ko = (size_t)(kt + 1) * 64 * 1536;
            const size_t vo = (size_t)(kt + 1) * 64;
            const int alt = cur ? 0 : 4096;
            gload_lds16(kg0 + ko, (void*)((u16*)Ks + alt + (ksd0 - (u16*)Ks)));
            gload_lds16(kg1 + ko, (void*)((u16*)Ks + alt + (ksd1 - (u16*)Ks)));
            gload_lds16(vg0 + vo, (void*)((u16*)Vs + alt + (vsd0 - (u16*)Vs)));
            gload_lds16(vg1 + vo, (void*)((u16*)Vs + alt + (vsd1 - (u16*)Vs)));
        }

        // S^T = K Q^T (swapped): sa[qb][n] reg r on lane (g,l15) = S'[k=16n+4g+r][q=qb*16+l15]
        f32x4 sa[2][4] = {};
        __builtin_amdgcn_s_setprio(1);
#pragma unroll
        for (int ks = 0; ks < 2; ++ks) {
            const int cb = ks * 4 + g;
            bf16x8 bk_[4];
#pragma unroll
            for (int n = 0; n < 4; ++n) {
                int row = n * 16 + l15;
                bk_[n] = *(const bf16x8*)&Ks[cur][row * 64 + ((cb ^ l7) << 3)];
            }
#pragma unroll
            for (int n = 0; n < 4; ++n)
#pragma unroll
                for (int qb = 0; qb < 2; ++qb)
                    sa[qb][n] = __builtin_amdgcn_mfma_f32_16x16x32_bf16(bk_[n], qf[qb][ks], sa[qb][n], 0, 0, 0);
        }
        __builtin_amdgcn_s_setprio(0);

        // P = exp2(S + mask*log2e)  (unshifted; bounded scores -> fp32-exact)
#pragma unroll
        for (int qb = 0; qb < 2; ++qb)
#pragma unroll
            for (int n = 0; n < 4; ++n)
#pragma unroll
                for (int r = 0; r < 4; ++r)
                    sa[qb][n][r] = __builtin_amdgcn_exp2f(fmaf(mv[n][r], LOG2E, sa[qb][n][r]));

        // row-sum accumulate (per qb)
#pragma unroll
        for (int qb = 0; qb < 2; ++qb) {
            f32x4 s4 = (sa[qb][0] + sa[qb][1]) + (sa[qb][2] + sa[qb][3]);
            float rs = (s4[0] + s4[1]) + (s4[2] + s4[3]);
            rs += __shfl_xor(rs, 16);
            rs += __shfl_xor(rs, 32);
            l_run[qb] += rs;
        }

        // P -> LDS: bf16x4 packed, ds_write_b64, swizzled (row = qb*16+l15, row&7 = l7)
#pragma unroll
        for (int qb = 0; qb < 2; ++qb)
#pragma unroll
            for (int n = 0; n < 4; ++n) {
                bf16x4 pk;
                pk[0] = (__bf16)sa[qb][n][0]; pk[1] = (__bf16)sa[qb][n][1];
                pk[2] = (__bf16)sa[qb][n][2]; pk[3] = (__bf16)sa[qb][n][3];
                int c16 = (2 * n + (g >> 1)) ^ l7;
                *(bf16x4*)(Pw + (qb * 16 + l15) * 64 + c16 * 8 + (g & 1) * 4) = pk;
            }

        // O += P @ V  (vb shared across qb)
        __builtin_amdgcn_s_setprio(1);
#pragma unroll
        for (int ks2 = 0; ks2 < 2; ++ks2) {
            const int sc = ((ks2 * 4 + g) ^ l7) << 3;
            bf16x8 pa[2];
#pragma unroll
            for (int qb = 0; qb < 2; ++qb)
                pa[qb] = *(const bf16x8*)(Pw + (qb * 16 + l15) * 64 + sc);
#pragma unroll
            for (int dn = 0; dn < 4; ++dn) {
                bf16x8 vb = *(const bf16x8*)&Vs[cur][(dn * 16 + l15) * 64 + sc];
#pragma unroll
                for (int qb = 0; qb < 2; ++qb)
                    o_acc[qb][dn] = __builtin_amdgcn_mfma_f32_16x16x32_bf16(pa[qb], vb, o_acc[qb][dn], 0, 0, 0);
            }
        }
        __builtin_amdgcn_s_setprio(0);

        asm volatile("s_waitcnt vmcnt(0)" ::: "memory");
        __syncthreads();
    }

    // normalize + store: o_acc[qb] row q = 4g+r needs l_run[qb] from lane l15=4g+r
#pragma unroll
    for (int qb = 0; qb < 2; ++qb)
#pragma unroll
        for (int r = 0; r < 4; ++r) {
            float lr = __shfl(l_run[qb], src_row + r);
            float inv = 1.f / lr;
#pragma unroll
            for (int dn = 0; dn < 4; ++dn) {
                int row = q0 + w * 32 + qb * 16 + (g << 2) + r;
                int col = h * 64 + dn * 16 + l15;
                Comb[(rowbase + row) * 768 + col] = f2b(o_acc[qb][dn][r] * inv);
            }
        }
}

// ---------------- launch ----------------

extern "C" void kernel_launch(void* const* d_in, const int* in_sizes, int n_in,
                              void* d_out, int out_size, void* d_ws, size_t ws_size,
                              hipStream_t stream) {
    (void)in_sizes; (void)n_in; (void)out_size; (void)ws_size;
    const float* x   = (const float*)d_in[0];
    const float* msk = (const float*)d_in[1];
    const float* Wq  = (const float*)d_in[2];
    const float* bq  = (const float*)d_in[3];
    const float* Wk  = (const float*)d_in[4];
    const float* bk  = (const float*)d_in[5];
    const float* Wv  = (const float*)d_in[6];
    const float* bv  = (const float*)d_in[7];
    const float* Wo  = (const float*)d_in[8];
    const float* bo  = (const float*)d_in[9];
    float* out = (float*)d_out;

    u16* Xb    = (u16*)d_ws;                          // 8192*768
    u16* WqkvT = Xb    + (size_t)8192 * 768;          // 2304*768
    u16* WoT   = WqkvT + (size_t)2304 * 768;          // 768*768
    u16* QKb   = WoT   + (size_t)768 * 768;           // 8192*1536 (q | k)
    u16* VT    = QKb   + (size_t)8192 * 1536;         // 768*8192 (transposed V)
    u16* Comb  = VT    + (size_t)768 * 8192;          // 8192*768
    float* bqkv = (float*)(Comb + (size_t)8192 * 768); // 2304

    cvt_x_kernel<<<6144, 256, 0, stream>>>(x, Xb, 8192 * 768 / 4);
    dim3 tb(32, 8);
    transpose_cvt_kernel<<<dim3(24, 24), tb, 0, stream>>>(Wq, WqkvT);
    transpose_cvt_kernel<<<dim3(24, 24), tb, 0, stream>>>(Wk, WqkvT + (size_t)768 * 768);
    transpose_cvt_kernel<<<dim3(24, 24), tb, 0, stream>>>(Wv, WqkvT + (size_t)2 * 768 * 768);
    transpose_cvt_kernel<<<dim3(24, 24), tb, 0, stream>>>(Wo, WoT);
    pack_bias_kernel<<<9, 256, 0, stream>>>(bq, bk, bv, bqkv);

    // QKV projection; Q/K -> QKb (ldc 1536), V -> VT transposed (fused)
    gemm_bt_kernel<u16, true><<<dim3(18, 64), 256, 0, stream>>>(
        Xb, WqkvT, bqkv, QKb, VT, 8192, 2304, 768, 1536);
    attn_kernel<<<dim3(16, 48), 256, 0, stream>>>(QKb, VT, msk, Comb);
    gemm_bt_kernel<float, false><<<dim3(6, 64), 256, 0, stream>>>(
        Comb, WoT, bo, out, nullptr, 8192, 768, 768, 768);
}

// Round 9
// 196.746 us; speedup vs baseline: 1.0752x; 1.0752x over previous
//
#include <hip/hip_runtime.h>
#include <hip/hip_bf16.h>

typedef __bf16 bf16x8 __attribute__((ext_vector_type(8)));
typedef __bf16 bf16x4 __attribute__((ext_vector_type(4)));
typedef float  f32x4  __attribute__((ext_vector_type(4)));
typedef unsigned short u16;
typedef unsigned int   u32;

#define GLOBAL_AS __attribute__((address_space(1)))
#define LDS_AS    __attribute__((address_space(3)))

#define LOG2E 1.44269504088896f

__device__ __forceinline__ void gload_lds16(const void* g, void* l) {
    __builtin_amdgcn_global_load_lds((GLOBAL_AS void*)g, (LDS_AS void*)l, 16, 0, 0);
}

__device__ __forceinline__ u16 f2b(float f) {
    union { float f; u32 u; } c; c.f = f;
    u32 u = c.u;
    u32 r = (u + 0x7FFFu + ((u >> 16) & 1u)) >> 16;   // RNE
    return (u16)r;
}

// ---------------- conversion kernels ----------------

__global__ void cvt_x_kernel(const float* __restrict__ x, u16* __restrict__ out, int n4) {
    int i = blockIdx.x * blockDim.x + threadIdx.x;
    if (i < n4) {
        float4 v = ((const float4*)x)[i];
        u16 o[4] = { f2b(v.x), f2b(v.y), f2b(v.z), f2b(v.w) };
        ((uint2*)out)[i] = *(uint2*)o;
    }
}

// dst[j][k] = src[k][j] (768x768), f32 -> bf16
__global__ void transpose_cvt_kernel(const float* __restrict__ src, u16* __restrict__ dst) {
    __shared__ float tile[32][33];
    int jt = blockIdx.x * 32, kt = blockIdx.y * 32;
    int tx = threadIdx.x, ty = threadIdx.y;           // block (32,8)
#pragma unroll
    for (int i = 0; i < 4; ++i)
        tile[ty + i * 8][tx] = src[(size_t)(kt + ty + i * 8) * 768 + jt + tx];
    __syncthreads();
#pragma unroll
    for (int i = 0; i < 4; ++i)
        dst[(size_t)(jt + ty + i * 8) * 768 + kt + tx] = f2b(tile[tx][ty + i * 8]);
}

__global__ void pack_bias_kernel(const float* __restrict__ bq, const float* __restrict__ bk,
                                 const float* __restrict__ bv, float* __restrict__ out) {
    int i = blockIdx.x * blockDim.x + threadIdx.x;
    if (i < 2304) out[i] = (i < 768) ? bq[i] : (i < 1536 ? bk[i - 768] : bv[i - 1536]);
}

// ---------------- GEMM 128x128: C[M][ldc] = A[M][K] @ Bt[N][K]^T + bias ----------------
// VSPLIT: output cols [0,1536) -> C (ldc), cols [1536,2304) -> VT[col-1536][row] (transposed,
// 8B packed stores; fuses the V transpose into the epilogue).
template <typename OutT, bool VSPLIT>
__global__ __launch_bounds__(256) void gemm_bt_kernel(
    const u16* __restrict__ A, const u16* __restrict__ Bt,
    const float* __restrict__ bias, OutT* __restrict__ C, u16* __restrict__ VT,
    int M, int N, int K, int ldc)
{
    __shared__ u16 As[128 * 64];
    __shared__ u16 Bs[128 * 64];
    const int lane = threadIdx.x & 63;
    const int w    = threadIdx.x >> 6;
    const int wr   = w >> 1, wc = w & 1;              // 2x2 waves -> 64x64 each
    const int m0   = blockIdx.y * 128, n0 = blockIdx.x * 128;

    f32x4 acc[4][4] = {};

    for (int k0 = 0; k0 < K; k0 += 64) {
        __syncthreads();
#pragma unroll
        for (int i = 0; i < 4; ++i) {
            int ci0 = w * 64 + i * 256;               // wave-uniform chunk base
            int ci  = ci0 + lane;
            int row = ci >> 3, col = (ci & 7) << 3;
            gload_lds16(A  + (size_t)(m0 + row) * K + k0 + col, (void*)(As + ci0 * 8));
            gload_lds16(Bt + (size_t)(n0 + row) * K + k0 + col, (void*)(Bs + ci0 * 8));
        }
        asm volatile("s_waitcnt vmcnt(0)" ::: "memory");
        __syncthreads();

#pragma unroll
        for (int ks = 0; ks < 2; ++ks) {
            const int koff = ks * 32 + (lane >> 4) * 8;
            bf16x8 af[4], bfr[4];
#pragma unroll
            for (int i = 0; i < 4; ++i)
                af[i] = *(const bf16x8*)&As[(wr * 64 + i * 16 + (lane & 15)) * 64 + koff];
#pragma unroll
            for (int j = 0; j < 4; ++j)
                bfr[j] = *(const bf16x8*)&Bs[(wc * 64 + j * 16 + (lane & 15)) * 64 + koff];
#pragma unroll
            for (int i = 0; i < 4; ++i)
#pragma unroll
                for (int j = 0; j < 4; ++j)
                    acc[i][j] = __builtin_amdgcn_mfma_f32_16x16x32_bf16(af[i], bfr[j], acc[i][j], 0, 0, 0);
        }
    }

    const bool vblk = VSPLIT && (n0 >= 1536);         // uniform per block (1536 % 128 == 0)
#pragma unroll
    for (int j = 0; j < 4; ++j) {
        int col = n0 + wc * 64 + j * 16 + (lane & 15);
        float bv = bias[col];
#pragma unroll
        for (int i = 0; i < 4; ++i) {
            int row = m0 + wr * 64 + i * 16 + ((lane >> 4) << 2);
            if (vblk) {
                u16 o[4];
#pragma unroll
                for (int r = 0; r < 4; ++r) o[r] = f2b(acc[i][j][r] + bv);
                *(uint2*)(VT + (size_t)(col - 1536) * 8192 + row) = *(uint2*)o;
            } else {
#pragma unroll
                for (int r = 0; r < 4; ++r) {
                    float v = acc[i][j][r] + bv;
                    if constexpr (sizeof(OutT) == 2)
                        C[(size_t)(row + r) * ldc + col] = (OutT)f2b(v);
                    else
                        C[(size_t)(row + r) * ldc + col] = (OutT)v;
                }
            }
        }
    }
}

// ---------------- GEMM 64x128 (f32 out): for small-N output projection ----------------
// BM=64 tile -> grid (N/128, M/64): 768 blocks = 3/CU (vs 1.5/CU with 128x128).
__global__ __launch_bounds__(256) void gemm_bt64_kernel(
    const u16* __restrict__ A, const u16* __restrict__ Bt,
    const float* __restrict__ bias, float* __restrict__ C,
    int M, int N, int K, int ldc)
{
    __shared__ u16 As[64 * 64];                       // 8 KB
    __shared__ u16 Bs[128 * 64];                      // 16 KB
    const int lane = threadIdx.x & 63;
    const int w    = threadIdx.x >> 6;
    const int wr   = w >> 1, wc = w & 1;              // 2x2 waves -> 32x64 each
    const int m0   = blockIdx.y * 64, n0 = blockIdx.x * 128;

    f32x4 acc[2][4] = {};

    for (int k0 = 0; k0 < K; k0 += 64) {
        __syncthreads();
#pragma unroll
        for (int i = 0; i < 2; ++i) {                 // A: 512 chunks
            int ci0 = w * 64 + i * 256;
            int ci  = ci0 + lane;
            int row = ci >> 3, col = (ci & 7) << 3;
            gload_lds16(A + (size_t)(m0 + row) * K + k0 + col, (void*)(As + ci0 * 8));
        }
#pragma unroll
        for (int i = 0; i < 4; ++i) {                 // B: 1024 chunks
            int ci0 = w * 64 + i * 256;
            int ci  = ci0 + lane;
            int row = ci >> 3, col = (ci & 7) << 3;
            gload_lds16(Bt + (size_t)(n0 + row) * K + k0 + col, (void*)(Bs + ci0 * 8));
        }
        asm volatile("s_waitcnt vmcnt(0)" ::: "memory");
        __syncthreads();

#pragma unroll
        for (int ks = 0; ks < 2; ++ks) {
            const int koff = ks * 32 + (lane >> 4) * 8;
            bf16x8 af[2], bfr[4];
#pragma unroll
            for (int i = 0; i < 2; ++i)
                af[i] = *(const bf16x8*)&As[(wr * 32 + i * 16 + (lane & 15)) * 64 + koff];
#pragma unroll
            for (int j = 0; j < 4; ++j)
                bfr[j] = *(const bf16x8*)&Bs[(wc * 64 + j * 16 + (lane & 15)) * 64 + koff];
#pragma unroll
            for (int i = 0; i < 2; ++i)
#pragma unroll
                for (int j = 0; j < 4; ++j)
                    acc[i][j] = __builtin_amdgcn_mfma_f32_16x16x32_bf16(af[i], bfr[j], acc[i][j], 0, 0, 0);
        }
    }

#pragma unroll
    for (int j = 0; j < 4; ++j) {
        int col = n0 + wc * 64 + j * 16 + (lane & 15);
        float bv = bias[col];
#pragma unroll
        for (int i = 0; i < 2; ++i) {
            int row = m0 + wr * 32 + i * 16 + ((lane >> 4) << 2);
#pragma unroll
            for (int r = 0; r < 4; ++r)
                C[(size_t)(row + r) * ldc + col] = acc[i][j][r] + bv;
        }
    }
}

// ---------------- flash attention v9 (= v7 + deferred l-reduction) ----------------
// QK: [B*S][1536] bf16 (q | k).  VT: [768 = h*64+d][8192 = b*2048+s] bf16.
// QBLK=64 (16 q/wave), KVBLK=64, grid 1536 (~4 blocks/CU resident, backfill).
// Swapped QK^T (S^T[k][q], k lane-local), UNSHIFTED exp2 softmax (scores bounded),
// dbuf K/V + 1 barrier/iter, XOR-swizzled LDS. l-sum: per-lane f32x4 partial only
// (cross-lane reduce ONCE at epilogue; sum over k is order-independent) -> removes
// the 2-bpermute serial chain from every iteration.
__global__ __launch_bounds__(256) void attn_kernel(
    const u16* __restrict__ QK, const u16* __restrict__ VT,
    const float* __restrict__ mask, u16* __restrict__ Comb)
{
    __shared__ u16 Ks[2][64 * 64];     // 16 KB
    __shared__ u16 Vs[2][64 * 64];     // 16 KB
    __shared__ u16 Pq[4 * 16 * 64];    // 8 KB   -> total 40 KB = 4 blocks/CU
    const int lane = threadIdx.x & 63;
    const int w    = threadIdx.x >> 6;
    const int g    = lane >> 4;
    const int l15  = lane & 15;
    const int l7   = lane & 7;
    const int q0   = blockIdx.x * 64;
    const int bh   = blockIdx.y;
    const int b    = bh / 12, h = bh % 12;
    const size_t rowbase = (size_t)b * 2048;
    const u16* Qg = QK + rowbase * 1536 + h * 64;
    const u16* Kg = QK + rowbase * 1536 + 768 + h * 64;
    const u16* Vg = VT + (size_t)(h * 64) * 8192 + b * 2048;  // row d (stride 8192), col s
    const float* mbase = mask + b * 2048 + (g << 2);

    // hoisted per-lane staging addresses (affine in kt)
    const int sci  = w * 64 + lane;                   // chunk index for i=0 (i=1: +256)
    const int srow = sci >> 3;                        // k-row / d-row
    const int kc   = ((sci & 7) ^ (srow & 7)) << 3;   // swizzle col
    const u16* kg0 = Kg + (size_t)srow * 1536 + kc;
    const u16* kg1 = Kg + (size_t)(srow + 32) * 1536 + kc;
    const u16* vg0 = Vg + (size_t)srow * 8192 + kc;
    const u16* vg1 = Vg + (size_t)(srow + 32) * 8192 + kc;
    u16* const ksd0 = (u16*)Ks + (w * 64) * 8;        // LDS dest (buffer 0); +4096 for buffer 1
    u16* const ksd1 = ksd0 + 256 * 8;
    u16* const vsd0 = (u16*)Vs + (w * 64) * 8;
    u16* const vsd1 = vsd0 + 256 * 8;

    // prologue: stage K/V tile 0
    gload_lds16(kg0, (void*)ksd0);
    gload_lds16(kg1, (void*)ksd1);
    gload_lds16(vg0, (void*)vsd0);
    gload_lds16(vg1, (void*)vsd1);

    // Q fragments scaled by 0.125 * log2(e)  (exp2-domain softmax)
    bf16x8 qf[2];
#pragma unroll
    for (int ks = 0; ks < 2; ++ks) {
        int row = q0 + w * 16 + l15;
        int d   = ks * 32 + g * 8;
        bf16x8 v = *(const bf16x8*)(Qg + (size_t)row * 1536 + d);
        bf16x8 s;
#pragma unroll
        for (int j = 0; j < 8; ++j) s[j] = (__bf16)((float)v[j] * (0.125f * LOG2E));
        qf[ks] = s;
    }

    f32x4 o_acc[4] = {};
    f32x4 l_acc = { 0.f, 0.f, 0.f, 0.f };             // per-lane partial sums (k-slices)
    u16* Pw = Pq + w * 16 * 64;
    const int src_row = (lane & 48) + (g << 2);

    asm volatile("s_waitcnt vmcnt(0)" ::: "memory");
    __syncthreads();

    for (int kt = 0; kt < 32; ++kt) {
        const int cur = kt & 1;
        const int k0  = kt * 64;

        // mask loads first (vm ops 1-4): their waitcnt won't drain staging
        f32x4 mv[4];
#pragma unroll
        for (int n = 0; n < 4; ++n)
            mv[n] = *(const f32x4*)(mbase + k0 + n * 16);

        // stage tile t+1 into alt buffer (affine addresses; peeled on last iter)
        if (kt < 31) {
            const size_t ko = (size_t)(kt + 1) * 64 * 1536;
            const size_t vo = (size_t)(kt + 1) * 64;
            const int alt = cur ? 0 : 4096;
            gload_lds16(kg0 + ko, (void*)((u16*)Ks + alt + (ksd0 - (u16*)Ks)));
            gload_lds16(kg1 + ko, (void*)((u16*)Ks + alt + (ksd1 - (u16*)Ks)));
            gload_lds16(vg0 + vo, (void*)((u16*)Vs + alt + (vsd0 - (u16*)Vs)));
            gload_lds16(vg1 + vo, (void*)((u16*)Vs + alt + (vsd1 - (u16*)Vs)));
        }

        // S^T = K Q^T (swapped): sa[n] reg r on lane (g,l15) = S'[k=16n+4g+r][q=l15]
        f32x4 sa[4] = {};
        __builtin_amdgcn_s_setprio(1);
#pragma unroll
        for (int ks = 0; ks < 2; ++ks) {
            const int cb = ks * 4 + g;
            bf16x8 bk_[4];
#pragma unroll
            for (int n = 0; n < 4; ++n) {
                int row = n * 16 + l15;
                bk_[n] = *(const bf16x8*)&Ks[cur][row * 64 + ((cb ^ l7) << 3)];
            }
#pragma unroll
            for (int n = 0; n < 4; ++n)
                sa[n] = __builtin_amdgcn_mfma_f32_16x16x32_bf16(bk_[n], qf[ks], sa[n], 0, 0, 0);
        }
        __builtin_amdgcn_s_setprio(0);

        // P = exp2(S + mask*log2e)  (unshifted; bounded scores -> fp32-exact)
#pragma unroll
        for (int n = 0; n < 4; ++n)
#pragma unroll
            for (int r = 0; r < 4; ++r)
                sa[n][r] = __builtin_amdgcn_exp2f(fmaf(mv[n][r], LOG2E, sa[n][r]));

        // per-lane partial row-sum (no cross-lane work in-loop)
        l_acc += (sa[0] + sa[1]) + (sa[2] + sa[3]);

        // P -> LDS: bf16x4 packed, ds_write_b64, swizzled
#pragma unroll
        for (int n = 0; n < 4; ++n) {
            bf16x4 pk;
            pk[0] = (__bf16)sa[n][0]; pk[1] = (__bf16)sa[n][1];
            pk[2] = (__bf16)sa[n][2]; pk[3] = (__bf16)sa[n][3];
            int c16 = (2 * n + (g >> 1)) ^ l7;
            *(bf16x4*)(Pw + l15 * 64 + c16 * 8 + (g & 1) * 4) = pk;
        }

        // O += P @ V
        __builtin_amdgcn_s_setprio(1);
#pragma unroll
        for (int ks2 = 0; ks2 < 2; ++ks2) {
            const int sc = ((ks2 * 4 + g) ^ l7) << 3;
            bf16x8 pa = *(const bf16x8*)(Pw + l15 * 64 + sc);
#pragma unroll
            for (int dn = 0; dn < 4; ++dn) {
                bf16x8 vb = *(const bf16x8*)&Vs[cur][(dn * 16 + l15) * 64 + sc];
                o_acc[dn] = __builtin_amdgcn_mfma_f32_16x16x32_bf16(pa, vb, o_acc[dn], 0, 0, 0);
            }
        }
        __builtin_amdgcn_s_setprio(0);

        asm volatile("s_waitcnt vmcnt(0)" ::: "memory");
        __syncthreads();
    }

    // epilogue: finish l-reduction (once), normalize, store
    float l_run = (l_acc[0] + l_acc[1]) + (l_acc[2] + l_acc[3]);
    l_run += __shfl_xor(l_run, 16);
    l_run += __shfl_xor(l_run, 32);
#pragma unroll
    for (int r = 0; r < 4; ++r) {
        float lr = __shfl(l_run, src_row + r);
        float inv = 1.f / lr;
#pragma unroll
        for (int dn = 0; dn < 4; ++dn) {
            int row = q0 + w * 16 + (g << 2) + r;
            int col = h * 64 + dn * 16 + l15;
            Comb[(rowbase + row) * 768 + col] = f2b(o_acc[dn][r] * inv);
        }
    }
}

// ---------------- launch ----------------

extern "C" void kernel_launch(void* const* d_in, const int* in_sizes, int n_in,
                              void* d_out, int out_size, void* d_ws, size_t ws_size,
                              hipStream_t stream) {
    (void)in_sizes; (void)n_in; (void)out_size; (void)ws_size;
    const float* x   = (const float*)d_in[0];
    const float* msk = (const float*)d_in[1];
    const float* Wq  = (const float*)d_in[2];
    const float* bq  = (const float*)d_in[3];
    const float* Wk  = (const float*)d_in[4];
    const float* bk  = (const float*)d_in[5];
    const float* Wv  = (const float*)d_in[6];
    const float* bv  = (const float*)d_in[7];
    const float* Wo  = (const float*)d_in[8];
    const float* bo  = (const float*)d_in[9];
    float* out = (float*)d_out;

    u16* Xb    = (u16*)d_ws;                          // 8192*768
    u16* WqkvT = Xb    + (size_t)8192 * 768;          // 2304*768
    u16* WoT   = WqkvT + (size_t)2304 * 768;          // 768*768
    u16* QKb   = WoT   + (size_t)768 * 768;           // 8192*1536 (q | k)
    u16* VT    = QKb   + (size_t)8192 * 1536;         // 768*8192 (transposed V)
    u16* Comb  = VT    + (size_t)768 * 8192;          // 8192*768
    float* bqkv = (float*)(Comb + (size_t)8192 * 768); // 2304

    cvt_x_kernel<<<6144, 256, 0, stream>>>(x, Xb, 8192 * 768 / 4);
    dim3 tb(32, 8);
    transpose_cvt_kernel<<<dim3(24, 24), tb, 0, stream>>>(Wq, WqkvT);
    transpose_cvt_kernel<<<dim3(24, 24), tb, 0, stream>>>(Wk, WqkvT + (size_t)768 * 768);
    transpose_cvt_kernel<<<dim3(24, 24), tb, 0, stream>>>(Wv, WqkvT + (size_t)2 * 768 * 768);
    transpose_cvt_kernel<<<dim3(24, 24), tb, 0, stream>>>(Wo, WoT);
    pack_bias_kernel<<<9, 256, 0, stream>>>(bq, bk, bv, bqkv);

    // QKV projection; Q/K -> QKb (ldc 1536), V -> VT transposed (fused)
    gemm_bt_kernel<u16, true><<<dim3(18, 64), 256, 0, stream>>>(
        Xb, WqkvT, bqkv, QKb, VT, 8192, 2304, 768, 1536);
    attn_kernel<<<dim3(32, 48), 256, 0, stream>>>(QKb, VT, msk, Comb);
    // out = Comb @ WoT^T + bo  (64x128 tiles: 768 blocks = 3/CU)
    gemm_bt64_kernel<<<dim3(6, 128), 256, 0, stream>>>(
        Comb, WoT, bo, out, 8192, 768, 768, 768);
}